// Round 11
// baseline (989.714 us; speedup 1.0000x reference)
//
#include <hip/hip_runtime.h>
#include <hip/hip_bf16.h>
#include <math.h>

// ============================================================================
// XCA transposed attention, bf16-MFMA, round 10:
//  - gemm_mfma rewrite: wave = 64Mx64N (4x4 frags, 4x reg reuse), A direct
//    global->reg (double-buffered), B reg-staged->LDS with issue-early/
//    write-late (T14). 4 ds_read : 16 MFMA. LDS 20.5KB. XCD-gather swizzle.
//  - attn_fused / dwconv / transposes unchanged.
// ============================================================================

#define HW 65536
#define IMW 256

typedef short bf16x8 __attribute__((ext_vector_type(8)));
typedef float f32x4  __attribute__((ext_vector_type(4)));

__device__ __forceinline__ float bf2f(ushort u) {
    return __uint_as_float((uint)u << 16);
}
__device__ __forceinline__ ushort f2bf(float f) {
    uint i = __float_as_uint(f);
    return (ushort)((i + 0x7FFFu + ((i >> 16) & 1u)) >> 16);
}

// ---- flat fp32 -> bf16 (weights)
__global__ __launch_bounds__(256) void cvt_f32_bf16(const float* __restrict__ s,
                                                    ushort* __restrict__ d, int n)
{
    int i = blockIdx.x * 256 + threadIdx.x;
    if (i < n) d[i] = f2bf(s[i]);
}

// ---- fp32 [R][C] -> bf16 [C][R] transpose+convert, 64x64 tiles, z-sliced
__global__ __launch_bounds__(256) void cvt_transpose_f32(const float* __restrict__ src,
                                                         ushort* __restrict__ dst,
                                                         int R, int C,
                                                         long ssS, long ssD)
{
    __shared__ ushort Ls[64][72];
    int t = threadIdx.x;
    long z = blockIdx.z;
    src += z * ssS; dst += z * ssD;
    int c0 = blockIdx.x * 64, r0 = blockIdx.y * 64;
    {
        int r = t >> 2, cs = t & 3;
        const float* gp = src + (size_t)(r0 + r) * C + c0 + cs * 16;
        ushort tmp[16];
        #pragma unroll
        for (int q = 0; q < 4; ++q) {
            float4 v = *(const float4*)(gp + q * 4);
            tmp[q*4+0] = f2bf(v.x); tmp[q*4+1] = f2bf(v.y);
            tmp[q*4+2] = f2bf(v.z); tmp[q*4+3] = f2bf(v.w);
        }
        *(uint4*)&Ls[r][cs * 16]     = *(uint4*)&tmp[0];
        *(uint4*)&Ls[r][cs * 16 + 8] = *(uint4*)&tmp[8];
    }
    __syncthreads();
    {
        int cc = t & 63, seg = t >> 6;
        ushort tmp[16];
        #pragma unroll
        for (int j = 0; j < 16; ++j) tmp[j] = Ls[seg * 16 + j][cc];
        ushort* op = dst + (size_t)(c0 + cc) * R + r0 + seg * 16;
        *(uint4*)(op)     = *(uint4*)&tmp[0];
        *(uint4*)(op + 8) = *(uint4*)&tmp[8];
    }
}

// ---- bf16 [R][C] -> bf16 [C][R] transpose, 64x64 tiles, z-sliced
__global__ __launch_bounds__(256) void transpose_bf16(const ushort* __restrict__ src,
                                                      ushort* __restrict__ dst,
                                                      int R, int C,
                                                      long ssS, long ssD)
{
    __shared__ ushort Ls[64][72];
    int t = threadIdx.x;
    long z = blockIdx.z;
    src += z * ssS; dst += z * ssD;
    int c0 = blockIdx.x * 64, r0 = blockIdx.y * 64;
    {
        int r = t >> 2, cs = t & 3;
        const ushort* gp = src + (size_t)(r0 + r) * C + c0 + cs * 16;
        *(uint4*)&Ls[r][cs * 16]     = *(const uint4*)(gp);
        *(uint4*)&Ls[r][cs * 16 + 8] = *(const uint4*)(gp + 8);
    }
    __syncthreads();
    {
        int cc = t & 63, seg = t >> 6;
        ushort tmp[16];
        #pragma unroll
        for (int j = 0; j < 16; ++j) tmp[j] = Ls[seg * 16 + j][cc];
        ushort* op = dst + (size_t)(c0 + cc) * R + r0 + seg * 16;
        *(uint4*)(op)     = *(uint4*)&tmp[0];
        *(uint4*)(op + 8) = *(uint4*)&tmp[8];
    }
}

// ---- V [b][384+r][256][256] -> Vt [s=b*192+r][256][256]^T
__global__ __launch_bounds__(256) void transpose_v(const ushort* __restrict__ post,
                                                   ushort* __restrict__ vt)
{
    __shared__ ushort Ls[64][72];
    int t = threadIdx.x;
    int s = blockIdx.z;
    int b = s / 192, r = s - b * 192;
    const ushort* src = post + ((size_t)b * 576 + 384 + r) * HW;
    ushort*       dst = vt + (size_t)s * HW;
    int c0 = blockIdx.x * 64, r0 = blockIdx.y * 64;
    {
        int rr = t >> 2, cs = t & 3;
        const ushort* gp = src + (size_t)(r0 + rr) * IMW + c0 + cs * 16;
        *(uint4*)&Ls[rr][cs * 16]     = *(const uint4*)(gp);
        *(uint4*)&Ls[rr][cs * 16 + 8] = *(const uint4*)(gp + 8);
    }
    __syncthreads();
    {
        int cc = t & 63, seg = t >> 6;
        ushort tmp[16];
        #pragma unroll
        for (int j = 0; j < 16; ++j) tmp[j] = Ls[seg * 16 + j][cc];
        ushort* op = dst + (size_t)(c0 + cc) * IMW + r0 + seg * 16;
        *(uint4*)(op)     = *(uint4*)&tmp[0];
        *(uint4*)(op + 8) = *(uint4*)&tmp[8];
    }
}

// ---- MFMA GEMM: D[m][n] = sum_k A[m][k]*B[n][k] (+bias[m]), K=192
// Block 64M x 256N (4 waves), wave 64M x 64N (4x4 16x16x32 frags).
// A: global->reg double-buffered. B: reg-staged -> LDS, issue-early/write-late.
// XCD-gather swizzle: NM m-blocks sharing a B-tile -> same XCD L2.
__global__ __launch_bounds__(256) void gemm_mfma(const ushort* __restrict__ A, int lda, long sliceA,
                                                 const ushort* __restrict__ B, int ldb, long sliceB,
                                                 void* __restrict__ Dp, int ldd, long sliceD,
                                                 const float* __restrict__ bias,
                                                 int outF32, int NM, int NN)
{
    // decode: r=lin&7, k=lin>>3, m=k%NM, g=(k/NM)*8+r, n=g%NN, z=g/NN
    int lin = blockIdx.x;
    int r8 = lin & 7, kk_ = lin >> 3;
    int m = kk_ % NM, fg = kk_ / NM;
    int g = fg * 8 + r8;
    int nt_ = g % NN;
    long z = g / NN;
    int m0 = m * 64;

    __shared__ ushort Xs[256][40];        // [n_local][k], pitch 80B
    int t = threadIdx.x, wv = t >> 6, lane = t & 63;
    int fr = lane & 15, fs = (lane >> 4) * 8;
    A += z * sliceA; B += z * sliceB;

    const ushort* bstage = B + (size_t)(nt_ * 256 + t) * ldb;   // + k0 + c*8
    const ushort* ap     = A + (size_t)(m0 + fr) * lda + fs;    // + i*16*lda + k0

    f32x4 acc[4][4];
    #pragma unroll
    for (int i = 0; i < 4; ++i)
        #pragma unroll
        for (int j = 0; j < 4; ++j) acc[i][j] = (f32x4){0.f, 0.f, 0.f, 0.f};

    uint4 bs[4];
    bf16x8 a_cur[4], a_nxt[4];
    // prologue: issue k0=0 loads
    #pragma unroll
    for (int c = 0; c < 4; ++c) bs[c] = *(const uint4*)(bstage + c * 8);
    #pragma unroll
    for (int i = 0; i < 4; ++i) a_cur[i] = *(const bf16x8*)(ap + (size_t)(i * 16) * lda);

    for (int kit = 0; kit < 6; ++kit) {
        int k0 = kit * 32;
        // write-late: b(kit) regs (issued one iter ago) -> LDS
        #pragma unroll
        for (int c = 0; c < 4; ++c) *(uint4*)&Xs[t][c * 8] = bs[c];
        // issue-early: next iteration's global loads, in flight through MFMA
        if (kit < 5) {
            #pragma unroll
            for (int c = 0; c < 4; ++c)
                bs[c] = *(const uint4*)(bstage + k0 + 32 + c * 8);
            #pragma unroll
            for (int i = 0; i < 4; ++i)
                a_nxt[i] = *(const bf16x8*)(ap + (size_t)(i * 16) * lda + k0 + 32);
        }
        __syncthreads();                  // Xs ready
        #pragma unroll
        for (int j = 0; j < 4; ++j) {
            bf16x8 b = *(const bf16x8*)&Xs[wv * 64 + j * 16 + fr][fs];
            #pragma unroll
            for (int i = 0; i < 4; ++i)
                acc[i][j] = __builtin_amdgcn_mfma_f32_16x16x32_bf16(a_cur[i], b, acc[i][j], 0, 0, 0);
        }
        __syncthreads();                  // all waves done reading Xs
        #pragma unroll
        for (int i = 0; i < 4; ++i) a_cur[i] = a_nxt[i];
    }

    int nw0 = nt_ * 256 + wv * 64;
    int rbase = (lane >> 4) * 4;
    if (outF32) {
        float* D = (float*)Dp + z * sliceD;
        #pragma unroll
        for (int i = 0; i < 4; ++i) {
            #pragma unroll
            for (int r_ = 0; r_ < 4; ++r_) {
                int mrow = m0 + i * 16 + rbase + r_;
                float bv = bias ? bias[mrow] : 0.f;
                #pragma unroll
                for (int j = 0; j < 4; ++j)
                    D[(size_t)mrow * ldd + nw0 + j * 16 + fr] = acc[i][j][r_] + bv;
            }
        }
    } else {
        ushort* D = (ushort*)Dp + z * sliceD;
        #pragma unroll
        for (int i = 0; i < 4; ++i) {
            #pragma unroll
            for (int r_ = 0; r_ < 4; ++r_) {
                int mrow = m0 + i * 16 + rbase + r_;
                float bv = bias ? bias[mrow] : 0.f;
                #pragma unroll
                for (int j = 0; j < 4; ++j)
                    D[(size_t)mrow * ldd + nw0 + j * 16 + fr] = f2bf(acc[i][j][r_] + bv);
            }
        }
    }
}

// ---- fused attention: per (m-tile 64, slice s): S=QK^T*t, softmax, O=P@Vt
// 1D grid with XCD-gather swizzle (4 m-tiles of a slice -> same XCD).
__global__ __launch_bounds__(256) void attn_fused(const ushort* __restrict__ post,
                                                  const ushort* __restrict__ vt,
                                                  const float* __restrict__ temp,
                                                  ushort* __restrict__ O)
{
    __shared__ ushort Ws[64][40];
    __shared__ ushort Xs[256][40];
    __shared__ ushort Ps[64][264];
    int t = threadIdx.x, wv = t >> 6, lane = t & 63;
    int lin = blockIdx.x;
    int r8 = lin & 7, k_ = lin >> 3;
    int mtile = k_ & 3, fg = k_ >> 2;
    int s = fg * 8 + r8;
    int b = s / 192, ch = s - b * 192;
    const ushort* Aq = post + ((size_t)b * 576 + ch) * HW;
    const ushort* Bk = Aq + (size_t)192 * HW;
    const ushort* Vt = vt + (size_t)s * HW;
    int m0 = mtile * 64;

    f32x4 acc[16];
    #pragma unroll
    for (int i = 0; i < 16; ++i) acc[i] = (f32x4){0.f, 0.f, 0.f, 0.f};

    for (int k0 = 0; k0 < 256; k0 += 32) {
        {   int r = t >> 2, ss = t & 3;
            *(uint4*)&Ws[r][ss * 8] =
                *(const uint4*)(Aq + (size_t)(m0 + r) * IMW + k0 + ss * 8);
        }
        {   const ushort* bp = Bk + (size_t)t * IMW + k0;
            #pragma unroll
            for (int ss = 0; ss < 4; ++ss)
                *(uint4*)&Xs[t][ss * 8] = *(const uint4*)(bp + ss * 8);
        }
        __syncthreads();
        bf16x8 a = *(const bf16x8*)&Ws[wv * 16 + (lane & 15)][(lane >> 4) * 8];
        #pragma unroll
        for (int nt = 0; nt < 16; ++nt) {
            bf16x8 bfrag = *(const bf16x8*)&Xs[nt * 16 + (lane & 15)][(lane >> 4) * 8];
            acc[nt] = __builtin_amdgcn_mfma_f32_16x16x32_bf16(a, bfrag, acc[nt], 0, 0, 0);
        }
        __syncthreads();
    }

    float tv = temp[ch >> 5];
    #pragma unroll
    for (int r_ = 0; r_ < 4; ++r_) {
        float v[16];
        float mx = -3.4e38f;
        #pragma unroll
        for (int nt = 0; nt < 16; ++nt) { v[nt] = acc[nt][r_] * tv; mx = fmaxf(mx, v[nt]); }
        #pragma unroll
        for (int sh = 1; sh < 16; sh <<= 1) mx = fmaxf(mx, __shfl_xor(mx, sh, 64));
        float sum = 0.f;
        #pragma unroll
        for (int nt = 0; nt < 16; ++nt) { v[nt] = __expf(v[nt] - mx); sum += v[nt]; }
        #pragma unroll
        for (int sh = 1; sh < 16; sh <<= 1) sum += __shfl_xor(sum, sh, 64);
        float inv = 1.f / sum;
        int ml = wv * 16 + (lane >> 4) * 4 + r_;
        #pragma unroll
        for (int nt = 0; nt < 16; ++nt)
            Ps[ml][(lane & 15) + nt * 16] = f2bf(v[nt] * inv);
    }

    f32x4 acc2[16];
    #pragma unroll
    for (int i = 0; i < 16; ++i) acc2[i] = (f32x4){0.f, 0.f, 0.f, 0.f};

    for (int y0 = 0; y0 < 256; y0 += 32) {
        {   const ushort* bp = Vt + (size_t)t * IMW + y0;
            #pragma unroll
            for (int ss = 0; ss < 4; ++ss)
                *(uint4*)&Xs[t][ss * 8] = *(const uint4*)(bp + ss * 8);
        }
        __syncthreads();
        bf16x8 a = *(const bf16x8*)&Ps[wv * 16 + (lane & 15)][y0 + (lane >> 4) * 8];
        #pragma unroll
        for (int nt = 0; nt < 16; ++nt) {
            bf16x8 bfrag = *(const bf16x8*)&Xs[nt * 16 + (lane & 15)][(lane >> 4) * 8];
            acc2[nt] = __builtin_amdgcn_mfma_f32_16x16x32_bf16(a, bfrag, acc2[nt], 0, 0, 0);
        }
        __syncthreads();
    }

    ushort* Op = O + (size_t)s * HW;
    int mrow = m0 + wv * 16 + (lane >> 4) * 4;
    int ncol = lane & 15;
    #pragma unroll
    for (int r_ = 0; r_ < 4; ++r_) {
        #pragma unroll
        for (int nt = 0; nt < 16; ++nt)
            Op[(size_t)(mrow + r_) * IMW + ncol + nt * 16] = f2bf(acc2[nt][r_]);
    }
}

// ---- depthwise 3x3 SAME + fused L2 row-norm, register-staged, shuffle halo
__global__ __launch_bounds__(256) void dw3x3_l2norm(const ushort* __restrict__ in,
                                                    const float* __restrict__ w,
                                                    const float* __restrict__ bias,
                                                    ushort* __restrict__ out)
{
    int t = threadIdx.x;
    int lane = t & 63, wv = t >> 6;
    int ch = blockIdx.y;
    int r0 = blockIdx.x * 16 + wv * 4;
    const ushort* img  = in  + ((size_t)blockIdx.z * 576 + ch) * HW;
    ushort*       outp = out + ((size_t)blockIdx.z * 576 + ch) * HW;
    int px = lane * 4;

    float rv[6][4], lv[6], rx[6];
    #pragma unroll
    for (int i = 0; i < 6; ++i) {
        int rr = r0 - 1 + i;
        if ((unsigned)rr <= 255u) {
            ushort4 cv = *(const ushort4*)&img[(size_t)rr * IMW + px];
            rv[i][0] = bf2f(cv.x); rv[i][1] = bf2f(cv.y);
            rv[i][2] = bf2f(cv.z); rv[i][3] = bf2f(cv.w);
        } else {
            rv[i][0] = rv[i][1] = rv[i][2] = rv[i][3] = 0.f;
        }
        float l = __shfl_up(rv[i][3], 1, 64);
        lv[i] = (lane == 0) ? 0.f : l;
        float r = __shfl_down(rv[i][0], 1, 64);
        rx[i] = (lane == 63) ? 0.f : r;
    }

    const float* wch = w + ch * 9;
    float bv = bias[ch];
    bool do_norm = (ch < 384);

    #pragma unroll
    for (int j = 0; j < 4; ++j) {
        float a0 = bv, a1 = bv, a2 = bv, a3 = bv;
        #pragma unroll
        for (int dy = 0; dy < 3; ++dy) {
            int i = j + dy;
            float w0 = wch[dy * 3], w1 = wch[dy * 3 + 1], w2 = wch[dy * 3 + 2];
            a0 += lv[i]    * w0 + rv[i][0] * w1 + rv[i][1] * w2;
            a1 += rv[i][0] * w0 + rv[i][1] * w1 + rv[i][2] * w2;
            a2 += rv[i][1] * w0 + rv[i][2] * w1 + rv[i][3] * w2;
            a3 += rv[i][2] * w0 + rv[i][3] * w1 + rx[i]    * w2;
        }
        if (do_norm) {
            float ss = a0 * a0 + a1 * a1 + a2 * a2 + a3 * a3;
            #pragma unroll
            for (int m = 1; m < 64; m <<= 1) ss += __shfl_xor(ss, m, 64);
            float inv = 1.0f / fmaxf(sqrtf(ss), 1e-12f);
            a0 *= inv; a1 *= inv; a2 *= inv; a3 *= inv;
        }
        ushort4 o;
        o.x = f2bf(a0); o.y = f2bf(a1); o.z = f2bf(a2); o.w = f2bf(a3);
        *(ushort4*)&outp[(size_t)(r0 + j) * IMW + px] = o;
    }
}

extern "C" void kernel_launch(void* const* d_in, const int* in_sizes, int n_in,
                              void* d_out, int out_size, void* d_ws, size_t ws_size,
                              hipStream_t stream)
{
    const float* x      = (const float*)d_in[0];
    const float* qkv_w  = (const float*)d_in[1];
    const float* qkv_b  = (const float*)d_in[2];
    const float* dw_w   = (const float*)d_in[3];
    const float* dw_b   = (const float*)d_in[4];
    const float* proj_w = (const float*)d_in[5];
    const float* proj_b = (const float*)d_in[6];
    const float* temp   = (const float*)d_in[7];
    float* out = (float*)d_out;

    const size_t off_wq   = 0;
    const size_t off_wp   = 110592;
    const size_t off_pre  = 262144;
    const size_t off_post = off_pre + (size_t)4 * 576 * HW;
    const size_t off_xt   = off_post + (size_t)4 * 576 * HW;
    const size_t total_us = off_xt + (size_t)4 * 192 * HW;
    if (ws_size < total_us * sizeof(ushort)) return;

    ushort* wsb  = (ushort*)d_ws;
    ushort* wq   = wsb + off_wq;
    ushort* wp   = wsb + off_wp;
    ushort* pre  = wsb + off_pre;
    ushort* post = wsb + off_post;
    ushort* xt   = wsb + off_xt;
    ushort* Obuf = pre;
    ushort* Otb  = pre + (size_t)4 * 192 * HW;

    const long SL = (long)192 * HW;

    cvt_f32_bf16<<<dim3(432), 256, 0, stream>>>(qkv_w, wq, 110592);
    cvt_f32_bf16<<<dim3(144), 256, 0, stream>>>(proj_w, wp, 36864);

    cvt_transpose_f32<<<dim3(1024, 3, 4), 256, 0, stream>>>(x, xt, 192, HW, SL, SL);
    // qkv: NM=9, NN=256, 4 batches -> 9216 blocks
    gemm_mfma<<<dim3(9 * 256 * 4), 256, 0, stream>>>(wq, 192, 0, xt, 192, SL,
                                                     pre, HW, (long)576 * HW,
                                                     qkv_b, 0, 9, 256);
    dw3x3_l2norm<<<dim3(16, 576, 4), 256, 0, stream>>>(pre, dw_w, dw_b, post);
    transpose_v<<<dim3(4, 4, 768), 256, 0, stream>>>(post, xt);
    attn_fused<<<dim3(4 * 768), 256, 0, stream>>>(post, xt, temp, Obuf);
    transpose_bf16<<<dim3(1024, 3, 4), 256, 0, stream>>>(Obuf, Otb, 192, HW, SL, SL);
    // proj: NM=3, NN=256, 4 batches -> 3072 blocks
    gemm_mfma<<<dim3(3 * 256 * 4), 256, 0, stream>>>(wp, 192, 0, Otb, 192, SL,
                                                     out, HW, SL,
                                                     proj_b, 1, 3, 256);
}

// Round 12
// 762.694 us; speedup vs baseline: 1.2977x; 1.2977x over previous
//
#include <hip/hip_runtime.h>
#include <hip/hip_bf16.h>
#include <math.h>

// ============================================================================
// XCA transposed attention, bf16-MFMA, round 11:
//  - gemm_mfma: round-7 staging (proven) + wave tile 64Mx64N (acc[4][4],
//    4x register reuse of A and B frags) -> 8 ds_read : 16 MFMA (was 17:16).
//  - attn_fused / dwconv / transposes unchanged from round 7.
// ============================================================================

#define HW 65536
#define IMW 256

typedef short bf16x8 __attribute__((ext_vector_type(8)));
typedef float f32x4  __attribute__((ext_vector_type(4)));

__device__ __forceinline__ float bf2f(ushort u) {
    return __uint_as_float((uint)u << 16);
}
__device__ __forceinline__ ushort f2bf(float f) {
    uint i = __float_as_uint(f);
    return (ushort)((i + 0x7FFFu + ((i >> 16) & 1u)) >> 16);
}

// ---- flat fp32 -> bf16 (weights)
__global__ __launch_bounds__(256) void cvt_f32_bf16(const float* __restrict__ s,
                                                    ushort* __restrict__ d, int n)
{
    int i = blockIdx.x * 256 + threadIdx.x;
    if (i < n) d[i] = f2bf(s[i]);
}

// ---- fp32 [R][C] -> bf16 [C][R] transpose+convert, 64x64 tiles, z-sliced
__global__ __launch_bounds__(256) void cvt_transpose_f32(const float* __restrict__ src,
                                                         ushort* __restrict__ dst,
                                                         int R, int C,
                                                         long ssS, long ssD)
{
    __shared__ ushort Ls[64][72];
    int t = threadIdx.x;
    long z = blockIdx.z;
    src += z * ssS; dst += z * ssD;
    int c0 = blockIdx.x * 64, r0 = blockIdx.y * 64;
    {
        int r = t >> 2, cs = t & 3;
        const float* gp = src + (size_t)(r0 + r) * C + c0 + cs * 16;
        ushort tmp[16];
        #pragma unroll
        for (int q = 0; q < 4; ++q) {
            float4 v = *(const float4*)(gp + q * 4);
            tmp[q*4+0] = f2bf(v.x); tmp[q*4+1] = f2bf(v.y);
            tmp[q*4+2] = f2bf(v.z); tmp[q*4+3] = f2bf(v.w);
        }
        *(uint4*)&Ls[r][cs * 16]     = *(uint4*)&tmp[0];
        *(uint4*)&Ls[r][cs * 16 + 8] = *(uint4*)&tmp[8];
    }
    __syncthreads();
    {
        int cc = t & 63, seg = t >> 6;
        ushort tmp[16];
        #pragma unroll
        for (int j = 0; j < 16; ++j) tmp[j] = Ls[seg * 16 + j][cc];
        ushort* op = dst + (size_t)(c0 + cc) * R + r0 + seg * 16;
        *(uint4*)(op)     = *(uint4*)&tmp[0];
        *(uint4*)(op + 8) = *(uint4*)&tmp[8];
    }
}

// ---- bf16 [R][C] -> bf16 [C][R] transpose, 64x64 tiles, z-sliced
__global__ __launch_bounds__(256) void transpose_bf16(const ushort* __restrict__ src,
                                                      ushort* __restrict__ dst,
                                                      int R, int C,
                                                      long ssS, long ssD)
{
    __shared__ ushort Ls[64][72];
    int t = threadIdx.x;
    long z = blockIdx.z;
    src += z * ssS; dst += z * ssD;
    int c0 = blockIdx.x * 64, r0 = blockIdx.y * 64;
    {
        int r = t >> 2, cs = t & 3;
        const ushort* gp = src + (size_t)(r0 + r) * C + c0 + cs * 16;
        *(uint4*)&Ls[r][cs * 16]     = *(const uint4*)(gp);
        *(uint4*)&Ls[r][cs * 16 + 8] = *(const uint4*)(gp + 8);
    }
    __syncthreads();
    {
        int cc = t & 63, seg = t >> 6;
        ushort tmp[16];
        #pragma unroll
        for (int j = 0; j < 16; ++j) tmp[j] = Ls[seg * 16 + j][cc];
        ushort* op = dst + (size_t)(c0 + cc) * R + r0 + seg * 16;
        *(uint4*)(op)     = *(uint4*)&tmp[0];
        *(uint4*)(op + 8) = *(uint4*)&tmp[8];
    }
}

// ---- V [b][384+r][256][256] -> Vt [s=b*192+r][256][256]^T
__global__ __launch_bounds__(256) void transpose_v(const ushort* __restrict__ post,
                                                   ushort* __restrict__ vt)
{
    __shared__ ushort Ls[64][72];
    int t = threadIdx.x;
    int s = blockIdx.z;
    int b = s / 192, r = s - b * 192;
    const ushort* src = post + ((size_t)b * 576 + 384 + r) * HW;
    ushort*       dst = vt + (size_t)s * HW;
    int c0 = blockIdx.x * 64, r0 = blockIdx.y * 64;
    {
        int rr = t >> 2, cs = t & 3;
        const ushort* gp = src + (size_t)(r0 + rr) * IMW + c0 + cs * 16;
        *(uint4*)&Ls[rr][cs * 16]     = *(const uint4*)(gp);
        *(uint4*)&Ls[rr][cs * 16 + 8] = *(const uint4*)(gp + 8);
    }
    __syncthreads();
    {
        int cc = t & 63, seg = t >> 6;
        ushort tmp[16];
        #pragma unroll
        for (int j = 0; j < 16; ++j) tmp[j] = Ls[seg * 16 + j][cc];
        ushort* op = dst + (size_t)(c0 + cc) * IMW + r0 + seg * 16;
        *(uint4*)(op)     = *(uint4*)&tmp[0];
        *(uint4*)(op + 8) = *(uint4*)&tmp[8];
    }
}

// ---- MFMA GEMM: D[m][n] = sum_k A[m][k]*B[n][k] (+bias[m])
// 1D grid, XCD-gather swizzle. Round-7 LDS staging (BK=32, pitch-40, 2
// barriers/iter). Wave tile 64Mx64N: acc[4][4], 8 ds_read : 16 MFMA.
__global__ __launch_bounds__(256) void gemm_mfma(const ushort* __restrict__ A, int lda, long sliceA,
                                                 const ushort* __restrict__ B, int ldb, long sliceB,
                                                 void* __restrict__ Dp, int ldd, long sliceD,
                                                 const float* __restrict__ bias,
                                                 int K, int outF32, int NM, int NN)
{
    // decode: r=lin&7, k=lin>>3, m=k%NM, g=(k/NM)*8+r, n=g%NN, z=g/NN
    int lin = blockIdx.x;
    int r8 = lin & 7, kk_ = lin >> 3;
    int m = kk_ % NM, fg = kk_ / NM;
    int g = fg * 8 + r8;
    int nt_ = g % NN;
    long z = g / NN;
    int m0 = m * 64;

    __shared__ ushort Ws[64][40];
    __shared__ ushort Xs[256][40];
    int t = threadIdx.x, wv = t >> 6, lane = t & 63;
    int fr = lane & 15, fs = (lane >> 4) * 8;
    A += z * sliceA; B += z * sliceB;
    int n0 = nt_ * 256;

    f32x4 acc[4][4];
    #pragma unroll
    for (int i = 0; i < 4; ++i)
        #pragma unroll
        for (int j = 0; j < 4; ++j) acc[i][j] = (f32x4){0.f, 0.f, 0.f, 0.f};

    for (int k0 = 0; k0 < K; k0 += 32) {
        {   int r = t >> 2, s = t & 3;
            *(uint4*)&Ws[r][s * 8] =
                *(const uint4*)(A + (size_t)(m0 + r) * lda + k0 + s * 8);
        }
        {   const ushort* bp = B + (size_t)(n0 + t) * ldb + k0;
            #pragma unroll
            for (int s = 0; s < 4; ++s)
                *(uint4*)&Xs[t][s * 8] = *(const uint4*)(bp + s * 8);
        }
        __syncthreads();
        bf16x8 a[4];
        #pragma unroll
        for (int i = 0; i < 4; ++i)
            a[i] = *(const bf16x8*)&Ws[i * 16 + fr][fs];
        #pragma unroll
        for (int j = 0; j < 4; ++j) {
            bf16x8 b = *(const bf16x8*)&Xs[wv * 64 + j * 16 + fr][fs];
            #pragma unroll
            for (int i = 0; i < 4; ++i)
                acc[i][j] = __builtin_amdgcn_mfma_f32_16x16x32_bf16(a[i], b, acc[i][j], 0, 0, 0);
        }
        __syncthreads();
    }

    int nw0 = n0 + wv * 64;
    int rbase = (lane >> 4) * 4;
    if (outF32) {
        float* D = (float*)Dp + z * sliceD;
        #pragma unroll
        for (int i = 0; i < 4; ++i) {
            #pragma unroll
            for (int r_ = 0; r_ < 4; ++r_) {
                int mrow = m0 + i * 16 + rbase + r_;
                float bv = bias ? bias[mrow] : 0.f;
                #pragma unroll
                for (int j = 0; j < 4; ++j)
                    D[(size_t)mrow * ldd + nw0 + j * 16 + fr] = acc[i][j][r_] + bv;
            }
        }
    } else {
        ushort* D = (ushort*)Dp + z * sliceD;
        #pragma unroll
        for (int i = 0; i < 4; ++i) {
            #pragma unroll
            for (int r_ = 0; r_ < 4; ++r_) {
                int mrow = m0 + i * 16 + rbase + r_;
                float bv = bias ? bias[mrow] : 0.f;
                #pragma unroll
                for (int j = 0; j < 4; ++j)
                    D[(size_t)mrow * ldd + nw0 + j * 16 + fr] = f2bf(acc[i][j][r_] + bv);
            }
        }
    }
}

// ---- fused attention: per (m-tile 64, slice s): S=QK^T*t, softmax, O=P@Vt
// 1D grid with XCD-gather swizzle (4 m-tiles of a slice -> same XCD).
__global__ __launch_bounds__(256) void attn_fused(const ushort* __restrict__ post,
                                                  const ushort* __restrict__ vt,
                                                  const float* __restrict__ temp,
                                                  ushort* __restrict__ O)
{
    __shared__ ushort Ws[64][40];
    __shared__ ushort Xs[256][40];
    __shared__ ushort Ps[64][264];
    int t = threadIdx.x, wv = t >> 6, lane = t & 63;
    int lin = blockIdx.x;
    int r8 = lin & 7, k_ = lin >> 3;
    int mtile = k_ & 3, fg = k_ >> 2;
    int s = fg * 8 + r8;
    int b = s / 192, ch = s - b * 192;
    const ushort* Aq = post + ((size_t)b * 576 + ch) * HW;
    const ushort* Bk = Aq + (size_t)192 * HW;
    const ushort* Vt = vt + (size_t)s * HW;
    int m0 = mtile * 64;

    f32x4 acc[16];
    #pragma unroll
    for (int i = 0; i < 16; ++i) acc[i] = (f32x4){0.f, 0.f, 0.f, 0.f};

    for (int k0 = 0; k0 < 256; k0 += 32) {
        {   int r = t >> 2, ss = t & 3;
            *(uint4*)&Ws[r][ss * 8] =
                *(const uint4*)(Aq + (size_t)(m0 + r) * IMW + k0 + ss * 8);
        }
        {   const ushort* bp = Bk + (size_t)t * IMW + k0;
            #pragma unroll
            for (int ss = 0; ss < 4; ++ss)
                *(uint4*)&Xs[t][ss * 8] = *(const uint4*)(bp + ss * 8);
        }
        __syncthreads();
        bf16x8 a = *(const bf16x8*)&Ws[wv * 16 + (lane & 15)][(lane >> 4) * 8];
        #pragma unroll
        for (int nt = 0; nt < 16; ++nt) {
            bf16x8 bfrag = *(const bf16x8*)&Xs[nt * 16 + (lane & 15)][(lane >> 4) * 8];
            acc[nt] = __builtin_amdgcn_mfma_f32_16x16x32_bf16(a, bfrag, acc[nt], 0, 0, 0);
        }
        __syncthreads();
    }

    float tv = temp[ch >> 5];
    #pragma unroll
    for (int r_ = 0; r_ < 4; ++r_) {
        float v[16];
        float mx = -3.4e38f;
        #pragma unroll
        for (int nt = 0; nt < 16; ++nt) { v[nt] = acc[nt][r_] * tv; mx = fmaxf(mx, v[nt]); }
        #pragma unroll
        for (int sh = 1; sh < 16; sh <<= 1) mx = fmaxf(mx, __shfl_xor(mx, sh, 64));
        float sum = 0.f;
        #pragma unroll
        for (int nt = 0; nt < 16; ++nt) { v[nt] = __expf(v[nt] - mx); sum += v[nt]; }
        #pragma unroll
        for (int sh = 1; sh < 16; sh <<= 1) sum += __shfl_xor(sum, sh, 64);
        float inv = 1.f / sum;
        int ml = wv * 16 + (lane >> 4) * 4 + r_;
        #pragma unroll
        for (int nt = 0; nt < 16; ++nt)
            Ps[ml][(lane & 15) + nt * 16] = f2bf(v[nt] * inv);
    }

    f32x4 acc2[16];
    #pragma unroll
    for (int i = 0; i < 16; ++i) acc2[i] = (f32x4){0.f, 0.f, 0.f, 0.f};

    for (int y0 = 0; y0 < 256; y0 += 32) {
        {   const ushort* bp = Vt + (size_t)t * IMW + y0;
            #pragma unroll
            for (int ss = 0; ss < 4; ++ss)
                *(uint4*)&Xs[t][ss * 8] = *(const uint4*)(bp + ss * 8);
        }
        __syncthreads();
        bf16x8 a = *(const bf16x8*)&Ps[wv * 16 + (lane & 15)][y0 + (lane >> 4) * 8];
        #pragma unroll
        for (int nt = 0; nt < 16; ++nt) {
            bf16x8 bfrag = *(const bf16x8*)&Xs[nt * 16 + (lane & 15)][(lane >> 4) * 8];
            acc2[nt] = __builtin_amdgcn_mfma_f32_16x16x32_bf16(a, bfrag, acc2[nt], 0, 0, 0);
        }
        __syncthreads();
    }

    ushort* Op = O + (size_t)s * HW;
    int mrow = m0 + wv * 16 + (lane >> 4) * 4;
    int ncol = lane & 15;
    #pragma unroll
    for (int r_ = 0; r_ < 4; ++r_) {
        #pragma unroll
        for (int nt = 0; nt < 16; ++nt)
            Op[(size_t)(mrow + r_) * IMW + ncol + nt * 16] = f2bf(acc2[nt][r_]);
    }
}

// ---- depthwise 3x3 SAME + fused L2 row-norm, register-staged, shuffle halo
__global__ __launch_bounds__(256) void dw3x3_l2norm(const ushort* __restrict__ in,
                                                    const float* __restrict__ w,
                                                    const float* __restrict__ bias,
                                                    ushort* __restrict__ out)
{
    int t = threadIdx.x;
    int lane = t & 63, wv = t >> 6;
    int ch = blockIdx.y;
    int r0 = blockIdx.x * 16 + wv * 4;
    const ushort* img  = in  + ((size_t)blockIdx.z * 576 + ch) * HW;
    ushort*       outp = out + ((size_t)blockIdx.z * 576 + ch) * HW;
    int px = lane * 4;

    float rv[6][4], lv[6], rx[6];
    #pragma unroll
    for (int i = 0; i < 6; ++i) {
        int rr = r0 - 1 + i;
        if ((unsigned)rr <= 255u) {
            ushort4 cv = *(const ushort4*)&img[(size_t)rr * IMW + px];
            rv[i][0] = bf2f(cv.x); rv[i][1] = bf2f(cv.y);
            rv[i][2] = bf2f(cv.z); rv[i][3] = bf2f(cv.w);
        } else {
            rv[i][0] = rv[i][1] = rv[i][2] = rv[i][3] = 0.f;
        }
        float l = __shfl_up(rv[i][3], 1, 64);
        lv[i] = (lane == 0) ? 0.f : l;
        float r = __shfl_down(rv[i][0], 1, 64);
        rx[i] = (lane == 63) ? 0.f : r;
    }

    const float* wch = w + ch * 9;
    float bv = bias[ch];
    bool do_norm = (ch < 384);

    #pragma unroll
    for (int j = 0; j < 4; ++j) {
        float a0 = bv, a1 = bv, a2 = bv, a3 = bv;
        #pragma unroll
        for (int dy = 0; dy < 3; ++dy) {
            int i = j + dy;
            float w0 = wch[dy * 3], w1 = wch[dy * 3 + 1], w2 = wch[dy * 3 + 2];
            a0 += lv[i]    * w0 + rv[i][0] * w1 + rv[i][1] * w2;
            a1 += rv[i][0] * w0 + rv[i][1] * w1 + rv[i][2] * w2;
            a2 += rv[i][1] * w0 + rv[i][2] * w1 + rv[i][3] * w2;
            a3 += rv[i][2] * w0 + rv[i][3] * w1 + rx[i]    * w2;
        }
        if (do_norm) {
            float ss = a0 * a0 + a1 * a1 + a2 * a2 + a3 * a3;
            #pragma unroll
            for (int m = 1; m < 64; m <<= 1) ss += __shfl_xor(ss, m, 64);
            float inv = 1.0f / fmaxf(sqrtf(ss), 1e-12f);
            a0 *= inv; a1 *= inv; a2 *= inv; a3 *= inv;
        }
        ushort4 o;
        o.x = f2bf(a0); o.y = f2bf(a1); o.z = f2bf(a2); o.w = f2bf(a3);
        *(ushort4*)&outp[(size_t)(r0 + j) * IMW + px] = o;
    }
}

extern "C" void kernel_launch(void* const* d_in, const int* in_sizes, int n_in,
                              void* d_out, int out_size, void* d_ws, size_t ws_size,
                              hipStream_t stream)
{
    const float* x      = (const float*)d_in[0];
    const float* qkv_w  = (const float*)d_in[1];
    const float* qkv_b  = (const float*)d_in[2];
    const float* dw_w   = (const float*)d_in[3];
    const float* dw_b   = (const float*)d_in[4];
    const float* proj_w = (const float*)d_in[5];
    const float* proj_b = (const float*)d_in[6];
    const float* temp   = (const float*)d_in[7];
    float* out = (float*)d_out;

    const size_t off_wq   = 0;
    const size_t off_wp   = 110592;
    const size_t off_pre  = 262144;
    const size_t off_post = off_pre + (size_t)4 * 576 * HW;
    const size_t off_xt   = off_post + (size_t)4 * 576 * HW;
    const size_t total_us = off_xt + (size_t)4 * 192 * HW;
    if (ws_size < total_us * sizeof(ushort)) return;

    ushort* wsb  = (ushort*)d_ws;
    ushort* wq   = wsb + off_wq;
    ushort* wp   = wsb + off_wp;
    ushort* pre  = wsb + off_pre;
    ushort* post = wsb + off_post;
    ushort* xt   = wsb + off_xt;
    ushort* Obuf = pre;
    ushort* Otb  = pre + (size_t)4 * 192 * HW;

    const long SL = (long)192 * HW;

    cvt_f32_bf16<<<dim3(432), 256, 0, stream>>>(qkv_w, wq, 110592);
    cvt_f32_bf16<<<dim3(144), 256, 0, stream>>>(proj_w, wp, 36864);

    cvt_transpose_f32<<<dim3(1024, 3, 4), 256, 0, stream>>>(x, xt, 192, HW, SL, SL);
    // qkv: NM=9, NN=256, 4 batches -> 9216 blocks
    gemm_mfma<<<dim3(9 * 256 * 4), 256, 0, stream>>>(wq, 192, 0, xt, 192, SL,
                                                     pre, HW, (long)576 * HW,
                                                     qkv_b, 192, 0, 9, 256);
    dw3x3_l2norm<<<dim3(16, 576, 4), 256, 0, stream>>>(pre, dw_w, dw_b, post);
    transpose_v<<<dim3(4, 4, 768), 256, 0, stream>>>(post, xt);
    attn_fused<<<dim3(4 * 768), 256, 0, stream>>>(post, xt, temp, Obuf);
    transpose_bf16<<<dim3(1024, 3, 4), 256, 0, stream>>>(Obuf, Otb, 192, HW, SL, SL);
    // proj: NM=3, NN=256, 4 batches -> 3072 blocks
    gemm_mfma<<<dim3(3 * 256 * 4), 256, 0, stream>>>(wp, 192, 0, Otb, 192, SL,
                                                     out, HW, SL,
                                                     proj_b, 192, 1, 3, 256);
}

// Round 13
// 700.920 us; speedup vs baseline: 1.4120x; 1.0881x over previous
//
#include <hip/hip_runtime.h>
#include <hip/hip_bf16.h>
#include <math.h>

// ============================================================================
// XCA transposed attention, bf16-MFMA, round 12:
//  - gemm_mfma + attn_fused staging via __builtin_amdgcn_global_load_lds
//    (width 16), linear LDS [rows][32] with both-sides XOR slot swizzle:
//    write: chunk = (lane&3) ^ ((lane>>3)&3)  (pre-swizzled global source)
//    read : slot  = sg ^ ((fr>>1)&3)
//    -> no VGPR round-trip, no ds_write, conflict-free (2-way) ds_read_b128.
//  - everything else unchanged from round 11 (742/762-us lineage).
// ============================================================================

#define HW 65536
#define IMW 256

typedef short bf16x8 __attribute__((ext_vector_type(8)));
typedef float f32x4  __attribute__((ext_vector_type(4)));

__device__ __forceinline__ float bf2f(ushort u) {
    return __uint_as_float((uint)u << 16);
}
__device__ __forceinline__ ushort f2bf(float f) {
    uint i = __float_as_uint(f);
    return (ushort)((i + 0x7FFFu + ((i >> 16) & 1u)) >> 16);
}

__device__ __forceinline__ void gload16(const ushort* g, ushort* l) {
    __builtin_amdgcn_global_load_lds(
        (const __attribute__((address_space(1))) void*)g,
        (__attribute__((address_space(3))) void*)l,
        16, 0, 0);
}

// ---- flat fp32 -> bf16 (weights)
__global__ __launch_bounds__(256) void cvt_f32_bf16(const float* __restrict__ s,
                                                    ushort* __restrict__ d, int n)
{
    int i = blockIdx.x * 256 + threadIdx.x;
    if (i < n) d[i] = f2bf(s[i]);
}

// ---- fp32 [R][C] -> bf16 [C][R] transpose+convert, 64x64 tiles, z-sliced
__global__ __launch_bounds__(256) void cvt_transpose_f32(const float* __restrict__ src,
                                                         ushort* __restrict__ dst,
                                                         int R, int C,
                                                         long ssS, long ssD)
{
    __shared__ ushort Ls[64][72];
    int t = threadIdx.x;
    long z = blockIdx.z;
    src += z * ssS; dst += z * ssD;
    int c0 = blockIdx.x * 64, r0 = blockIdx.y * 64;
    {
        int r = t >> 2, cs = t & 3;
        const float* gp = src + (size_t)(r0 + r) * C + c0 + cs * 16;
        ushort tmp[16];
        #pragma unroll
        for (int q = 0; q < 4; ++q) {
            float4 v = *(const float4*)(gp + q * 4);
            tmp[q*4+0] = f2bf(v.x); tmp[q*4+1] = f2bf(v.y);
            tmp[q*4+2] = f2bf(v.z); tmp[q*4+3] = f2bf(v.w);
        }
        *(uint4*)&Ls[r][cs * 16]     = *(uint4*)&tmp[0];
        *(uint4*)&Ls[r][cs * 16 + 8] = *(uint4*)&tmp[8];
    }
    __syncthreads();
    {
        int cc = t & 63, seg = t >> 6;
        ushort tmp[16];
        #pragma unroll
        for (int j = 0; j < 16; ++j) tmp[j] = Ls[seg * 16 + j][cc];
        ushort* op = dst + (size_t)(c0 + cc) * R + r0 + seg * 16;
        *(uint4*)(op)     = *(uint4*)&tmp[0];
        *(uint4*)(op + 8) = *(uint4*)&tmp[8];
    }
}

// ---- bf16 [R][C] -> bf16 [C][R] transpose, 64x64 tiles, z-sliced
__global__ __launch_bounds__(256) void transpose_bf16(const ushort* __restrict__ src,
                                                      ushort* __restrict__ dst,
                                                      int R, int C,
                                                      long ssS, long ssD)
{
    __shared__ ushort Ls[64][72];
    int t = threadIdx.x;
    long z = blockIdx.z;
    src += z * ssS; dst += z * ssD;
    int c0 = blockIdx.x * 64, r0 = blockIdx.y * 64;
    {
        int r = t >> 2, cs = t & 3;
        const ushort* gp = src + (size_t)(r0 + r) * C + c0 + cs * 16;
        *(uint4*)&Ls[r][cs * 16]     = *(const uint4*)(gp);
        *(uint4*)&Ls[r][cs * 16 + 8] = *(const uint4*)(gp + 8);
    }
    __syncthreads();
    {
        int cc = t & 63, seg = t >> 6;
        ushort tmp[16];
        #pragma unroll
        for (int j = 0; j < 16; ++j) tmp[j] = Ls[seg * 16 + j][cc];
        ushort* op = dst + (size_t)(c0 + cc) * R + r0 + seg * 16;
        *(uint4*)(op)     = *(uint4*)&tmp[0];
        *(uint4*)(op + 8) = *(uint4*)&tmp[8];
    }
}

// ---- V [b][384+r][256][256] -> Vt [s=b*192+r][256][256]^T
__global__ __launch_bounds__(256) void transpose_v(const ushort* __restrict__ post,
                                                   ushort* __restrict__ vt)
{
    __shared__ ushort Ls[64][72];
    int t = threadIdx.x;
    int s = blockIdx.z;
    int b = s / 192, r = s - b * 192;
    const ushort* src = post + ((size_t)b * 576 + 384 + r) * HW;
    ushort*       dst = vt + (size_t)s * HW;
    int c0 = blockIdx.x * 64, r0 = blockIdx.y * 64;
    {
        int rr = t >> 2, cs = t & 3;
        const ushort* gp = src + (size_t)(r0 + rr) * IMW + c0 + cs * 16;
        *(uint4*)&Ls[rr][cs * 16]     = *(const uint4*)(gp);
        *(uint4*)&Ls[rr][cs * 16 + 8] = *(const uint4*)(gp + 8);
    }
    __syncthreads();
    {
        int cc = t & 63, seg = t >> 6;
        ushort tmp[16];
        #pragma unroll
        for (int j = 0; j < 16; ++j) tmp[j] = Ls[seg * 16 + j][cc];
        ushort* op = dst + (size_t)(c0 + cc) * IMW + r0 + seg * 16;
        *(uint4*)(op)     = *(uint4*)&tmp[0];
        *(uint4*)(op + 8) = *(uint4*)&tmp[8];
    }
}

// ---- MFMA GEMM: D[m][n] = sum_k A[m][k]*B[n][k] (+bias[m])
// 1D grid, XCD-gather swizzle. Staging via global_load_lds (16B/lane) into
// linear LDS [rows][32] with XOR slot swizzle. Wave tile 64Mx64N, acc[4][4].
__global__ __launch_bounds__(256) void gemm_mfma(const ushort* __restrict__ A, int lda, long sliceA,
                                                 const ushort* __restrict__ B, int ldb, long sliceB,
                                                 void* __restrict__ Dp, int ldd, long sliceD,
                                                 const float* __restrict__ bias,
                                                 int K, int outF32, int NM, int NN)
{
    // decode: r=lin&7, k=lin>>3, m=k%NM, g=(k/NM)*8+r, n=g%NN, z=g/NN
    int lin = blockIdx.x;
    int r8 = lin & 7, kk_ = lin >> 3;
    int m = kk_ % NM, fg = kk_ / NM;
    int g = fg * 8 + r8;
    int nt_ = g % NN;
    long z = g / NN;
    int m0 = m * 64;
    int n0 = nt_ * 256;

    __shared__ ushort Ws[64][32];     // A tile, linear (swizzled chunks)
    __shared__ ushort Xs[256][32];    // B tile, linear (swizzled chunks)
    int t = threadIdx.x, wv = t >> 6, lane = t & 63;
    int fr = lane & 15, sg = lane >> 4;
    A += z * sliceA; B += z * sliceB;

    // staging: wave w issue -> rows (i*64 + w*16 + lane>>2), chunk swizzled
    int rl   = wv * 16 + (lane >> 2);               // row within 64-row group
    int chnk = (lane & 3) ^ ((lane >> 3) & 3);      // swizzled k-chunk
    const ushort* srcA = A + (size_t)(m0 + rl) * lda + chnk * 8;
    const ushort* srcB0 = B + (size_t)(n0 +       rl) * ldb + chnk * 8;
    const ushort* srcB1 = B + (size_t)(n0 +  64 + rl) * ldb + chnk * 8;
    const ushort* srcB2 = B + (size_t)(n0 + 128 + rl) * ldb + chnk * 8;
    const ushort* srcB3 = B + (size_t)(n0 + 192 + rl) * ldb + chnk * 8;

    int sp = sg ^ ((fr >> 1) & 3);                  // read-side slot swizzle

    f32x4 acc[4][4];
    #pragma unroll
    for (int i = 0; i < 4; ++i)
        #pragma unroll
        for (int j = 0; j < 4; ++j) acc[i][j] = (f32x4){0.f, 0.f, 0.f, 0.f};

    for (int k0 = 0; k0 < K; k0 += 32) {
        gload16(srcA  + k0, &Ws[wv * 16][0]);
        gload16(srcB0 + k0, &Xs[      wv * 16][0]);
        gload16(srcB1 + k0, &Xs[ 64 + wv * 16][0]);
        gload16(srcB2 + k0, &Xs[128 + wv * 16][0]);
        gload16(srcB3 + k0, &Xs[192 + wv * 16][0]);
        __syncthreads();
        bf16x8 a[4];
        #pragma unroll
        for (int i = 0; i < 4; ++i)
            a[i] = *(const bf16x8*)&Ws[i * 16 + fr][sp * 8];
        #pragma unroll
        for (int j = 0; j < 4; ++j) {
            bf16x8 b = *(const bf16x8*)&Xs[wv * 64 + j * 16 + fr][sp * 8];
            #pragma unroll
            for (int i = 0; i < 4; ++i)
                acc[i][j] = __builtin_amdgcn_mfma_f32_16x16x32_bf16(a[i], b, acc[i][j], 0, 0, 0);
        }
        __syncthreads();
    }

    int nw0 = n0 + wv * 64;
    int rbase = sg * 4;
    if (outF32) {
        float* D = (float*)Dp + z * sliceD;
        #pragma unroll
        for (int i = 0; i < 4; ++i) {
            #pragma unroll
            for (int r_ = 0; r_ < 4; ++r_) {
                int mrow = m0 + i * 16 + rbase + r_;
                float bv = bias ? bias[mrow] : 0.f;
                #pragma unroll
                for (int j = 0; j < 4; ++j)
                    D[(size_t)mrow * ldd + nw0 + j * 16 + fr] = acc[i][j][r_] + bv;
            }
        }
    } else {
        ushort* D = (ushort*)Dp + z * sliceD;
        #pragma unroll
        for (int i = 0; i < 4; ++i) {
            #pragma unroll
            for (int r_ = 0; r_ < 4; ++r_) {
                int mrow = m0 + i * 16 + rbase + r_;
                float bv = bias ? bias[mrow] : 0.f;
                #pragma unroll
                for (int j = 0; j < 4; ++j)
                    D[(size_t)mrow * ldd + nw0 + j * 16 + fr] = f2bf(acc[i][j][r_] + bv);
            }
        }
    }
}

// ---- fused attention: per (m-tile 64, slice s): S=QK^T*t, softmax, O=P@Vt
// 1D grid, XCD-gather swizzle. Q/K/Vt staged via global_load_lds + swizzle.
__global__ __launch_bounds__(256) void attn_fused(const ushort* __restrict__ post,
                                                  const ushort* __restrict__ vt,
                                                  const float* __restrict__ temp,
                                                  ushort* __restrict__ O)
{
    __shared__ ushort Ws[64][32];     // Q tile
    __shared__ ushort Xs[256][32];    // K then Vt tile
    __shared__ ushort Ps[64][264];    // P (bf16)
    int t = threadIdx.x, wv = t >> 6, lane = t & 63;
    int fr = lane & 15, sg = lane >> 4;
    int lin = blockIdx.x;
    int r8 = lin & 7, k_ = lin >> 3;
    int mtile = k_ & 3, fg = k_ >> 2;
    int s = fg * 8 + r8;
    int b = s / 192, ch = s - b * 192;
    const ushort* Aq = post + ((size_t)b * 576 + ch) * HW;
    const ushort* Bk = Aq + (size_t)192 * HW;
    const ushort* Vt = vt + (size_t)s * HW;
    int m0 = mtile * 64;

    int rl   = wv * 16 + (lane >> 2);
    int chnk = (lane & 3) ^ ((lane >> 3) & 3);
    int sp   = sg ^ ((fr >> 1) & 3);
    const ushort* srcQ  = Aq + (size_t)(m0 + rl) * IMW + chnk * 8;
    const ushort* srcK0 = Bk + (size_t)(      rl) * IMW + chnk * 8;
    const ushort* srcK1 = Bk + (size_t)( 64 + rl) * IMW + chnk * 8;
    const ushort* srcK2 = Bk + (size_t)(128 + rl) * IMW + chnk * 8;
    const ushort* srcK3 = Bk + (size_t)(192 + rl) * IMW + chnk * 8;
    const ushort* srcV0 = Vt + (size_t)(      rl) * IMW + chnk * 8;
    const ushort* srcV1 = Vt + (size_t)( 64 + rl) * IMW + chnk * 8;
    const ushort* srcV2 = Vt + (size_t)(128 + rl) * IMW + chnk * 8;
    const ushort* srcV3 = Vt + (size_t)(192 + rl) * IMW + chnk * 8;

    f32x4 acc[16];
    #pragma unroll
    for (int i = 0; i < 16; ++i) acc[i] = (f32x4){0.f, 0.f, 0.f, 0.f};

    for (int k0 = 0; k0 < 256; k0 += 32) {
        gload16(srcQ  + k0, &Ws[wv * 16][0]);
        gload16(srcK0 + k0, &Xs[      wv * 16][0]);
        gload16(srcK1 + k0, &Xs[ 64 + wv * 16][0]);
        gload16(srcK2 + k0, &Xs[128 + wv * 16][0]);
        gload16(srcK3 + k0, &Xs[192 + wv * 16][0]);
        __syncthreads();
        bf16x8 a = *(const bf16x8*)&Ws[wv * 16 + fr][sp * 8];
        #pragma unroll
        for (int nt = 0; nt < 16; ++nt) {
            bf16x8 bfrag = *(const bf16x8*)&Xs[nt * 16 + fr][sp * 8];
            acc[nt] = __builtin_amdgcn_mfma_f32_16x16x32_bf16(a, bfrag, acc[nt], 0, 0, 0);
        }
        __syncthreads();
    }

    float tv = temp[ch >> 5];
    #pragma unroll
    for (int r_ = 0; r_ < 4; ++r_) {
        float v[16];
        float mx = -3.4e38f;
        #pragma unroll
        for (int nt = 0; nt < 16; ++nt) { v[nt] = acc[nt][r_] * tv; mx = fmaxf(mx, v[nt]); }
        #pragma unroll
        for (int sh = 1; sh < 16; sh <<= 1) mx = fmaxf(mx, __shfl_xor(mx, sh, 64));
        float sum = 0.f;
        #pragma unroll
        for (int nt = 0; nt < 16; ++nt) { v[nt] = __expf(v[nt] - mx); sum += v[nt]; }
        #pragma unroll
        for (int sh = 1; sh < 16; sh <<= 1) sum += __shfl_xor(sum, sh, 64);
        float inv = 1.f / sum;
        int ml = wv * 16 + sg * 4 + r_;
        #pragma unroll
        for (int nt = 0; nt < 16; ++nt)
            Ps[ml][fr + nt * 16] = f2bf(v[nt] * inv);
    }

    f32x4 acc2[16];
    #pragma unroll
    for (int i = 0; i < 16; ++i) acc2[i] = (f32x4){0.f, 0.f, 0.f, 0.f};

    for (int y0 = 0; y0 < 256; y0 += 32) {
        gload16(srcV0 + y0, &Xs[      wv * 16][0]);
        gload16(srcV1 + y0, &Xs[ 64 + wv * 16][0]);
        gload16(srcV2 + y0, &Xs[128 + wv * 16][0]);
        gload16(srcV3 + y0, &Xs[192 + wv * 16][0]);
        __syncthreads();
        bf16x8 a = *(const bf16x8*)&Ps[wv * 16 + fr][y0 + sg * 8];
        #pragma unroll
        for (int nt = 0; nt < 16; ++nt) {
            bf16x8 bfrag = *(const bf16x8*)&Xs[nt * 16 + fr][sp * 8];
            acc2[nt] = __builtin_amdgcn_mfma_f32_16x16x32_bf16(a, bfrag, acc2[nt], 0, 0, 0);
        }
        __syncthreads();
    }

    ushort* Op = O + (size_t)s * HW;
    int mrow = m0 + wv * 16 + sg * 4;
    #pragma unroll
    for (int r_ = 0; r_ < 4; ++r_) {
        #pragma unroll
        for (int nt = 0; nt < 16; ++nt)
            Op[(size_t)(mrow + r_) * IMW + fr + nt * 16] = f2bf(acc2[nt][r_]);
    }
}

// ---- depthwise 3x3 SAME + fused L2 row-norm, register-staged, shuffle halo
__global__ __launch_bounds__(256) void dw3x3_l2norm(const ushort* __restrict__ in,
                                                    const float* __restrict__ w,
                                                    const float* __restrict__ bias,
                                                    ushort* __restrict__ out)
{
    int t = threadIdx.x;
    int lane = t & 63, wv = t >> 6;
    int ch = blockIdx.y;
    int r0 = blockIdx.x * 16 + wv * 4;
    const ushort* img  = in  + ((size_t)blockIdx.z * 576 + ch) * HW;
    ushort*       outp = out + ((size_t)blockIdx.z * 576 + ch) * HW;
    int px = lane * 4;

    float rv[6][4], lv[6], rx[6];
    #pragma unroll
    for (int i = 0; i < 6; ++i) {
        int rr = r0 - 1 + i;
        if ((unsigned)rr <= 255u) {
            ushort4 cv = *(const ushort4*)&img[(size_t)rr * IMW + px];
            rv[i][0] = bf2f(cv.x); rv[i][1] = bf2f(cv.y);
            rv[i][2] = bf2f(cv.z); rv[i][3] = bf2f(cv.w);
        } else {
            rv[i][0] = rv[i][1] = rv[i][2] = rv[i][3] = 0.f;
        }
        float l = __shfl_up(rv[i][3], 1, 64);
        lv[i] = (lane == 0) ? 0.f : l;
        float r = __shfl_down(rv[i][0], 1, 64);
        rx[i] = (lane == 63) ? 0.f : r;
    }

    const float* wch = w + ch * 9;
    float bv = bias[ch];
    bool do_norm = (ch < 384);

    #pragma unroll
    for (int j = 0; j < 4; ++j) {
        float a0 = bv, a1 = bv, a2 = bv, a3 = bv;
        #pragma unroll
        for (int dy = 0; dy < 3; ++dy) {
            int i = j + dy;
            float w0 = wch[dy * 3], w1 = wch[dy * 3 + 1], w2 = wch[dy * 3 + 2];
            a0 += lv[i]    * w0 + rv[i][0] * w1 + rv[i][1] * w2;
            a1 += rv[i][0] * w0 + rv[i][1] * w1 + rv[i][2] * w2;
            a2 += rv[i][1] * w0 + rv[i][2] * w1 + rv[i][3] * w2;
            a3 += rv[i][2] * w0 + rv[i][3] * w1 + rx[i]    * w2;
        }
        if (do_norm) {
            float ss = a0 * a0 + a1 * a1 + a2 * a2 + a3 * a3;
            #pragma unroll
            for (int m = 1; m < 64; m <<= 1) ss += __shfl_xor(ss, m, 64);
            float inv = 1.0f / fmaxf(sqrtf(ss), 1e-12f);
            a0 *= inv; a1 *= inv; a2 *= inv; a3 *= inv;
        }
        ushort4 o;
        o.x = f2bf(a0); o.y = f2bf(a1); o.z = f2bf(a2); o.w = f2bf(a3);
        *(ushort4*)&outp[(size_t)(r0 + j) * IMW + px] = o;
    }
}

extern "C" void kernel_launch(void* const* d_in, const int* in_sizes, int n_in,
                              void* d_out, int out_size, void* d_ws, size_t ws_size,
                              hipStream_t stream)
{
    const float* x      = (const float*)d_in[0];
    const float* qkv_w  = (const float*)d_in[1];
    const float* qkv_b  = (const float*)d_in[2];
    const float* dw_w   = (const float*)d_in[3];
    const float* dw_b   = (const float*)d_in[4];
    const float* proj_w = (const float*)d_in[5];
    const float* proj_b = (const float*)d_in[6];
    const float* temp   = (const float*)d_in[7];
    float* out = (float*)d_out;

    const size_t off_wq   = 0;
    const size_t off_wp   = 110592;
    const size_t off_pre  = 262144;
    const size_t off_post = off_pre + (size_t)4 * 576 * HW;
    const size_t off_xt   = off_post + (size_t)4 * 576 * HW;
    const size_t total_us = off_xt + (size_t)4 * 192 * HW;
    if (ws_size < total_us * sizeof(ushort)) return;

    ushort* wsb  = (ushort*)d_ws;
    ushort* wq   = wsb + off_wq;
    ushort* wp   = wsb + off_wp;
    ushort* pre  = wsb + off_pre;
    ushort* post = wsb + off_post;
    ushort* xt   = wsb + off_xt;
    ushort* Obuf = pre;
    ushort* Otb  = pre + (size_t)4 * 192 * HW;

    const long SL = (long)192 * HW;

    cvt_f32_bf16<<<dim3(432), 256, 0, stream>>>(qkv_w, wq, 110592);
    cvt_f32_bf16<<<dim3(144), 256, 0, stream>>>(proj_w, wp, 36864);

    cvt_transpose_f32<<<dim3(1024, 3, 4), 256, 0, stream>>>(x, xt, 192, HW, SL, SL);
    // qkv: NM=9, NN=256, 4 batches -> 9216 blocks
    gemm_mfma<<<dim3(9 * 256 * 4), 256, 0, stream>>>(wq, 192, 0, xt, 192, SL,
                                                     pre, HW, (long)576 * HW,
                                                     qkv_b, 192, 0, 9, 256);
    dw3x3_l2norm<<<dim3(16, 576, 4), 256, 0, stream>>>(pre, dw_w, dw_b, post);
    transpose_v<<<dim3(4, 4, 768), 256, 0, stream>>>(post, xt);
    attn_fused<<<dim3(4 * 768), 256, 0, stream>>>(post, xt, temp, Obuf);
    transpose_bf16<<<dim3(1024, 3, 4), 256, 0, stream>>>(Obuf, Otb, 192, HW, SL, SL);
    // proj: NM=3, NN=256, 4 batches -> 3072 blocks
    gemm_mfma<<<dim3(3 * 256 * 4), 256, 0, stream>>>(wp, 192, 0, Otb, 192, SL,
                                                     out, HW, SL,
                                                     proj_b, 192, 1, 3, 256);
}

// Round 14
// 687.696 us; speedup vs baseline: 1.4392x; 1.0192x over previous
//
#include <hip/hip_runtime.h>
#include <hip/hip_bf16.h>
#include <math.h>

// ============================================================================
// XCA transposed attention, bf16-MFMA, round 13:
//  - gemm_mfma: double-buffered LDS (2x{A,B} = 40KB), global_load_lds staging
//    issued for tile k+1 BEFORE computing tile k, ONE __syncthreads per iter.
//    (round-12 swizzle kept: conflicts were 0.)
//  - attn_fused / dwconv / transposes unchanged from round 12 (700us lineage).
// ============================================================================

#define HW 65536
#define IMW 256

typedef short bf16x8 __attribute__((ext_vector_type(8)));
typedef float f32x4  __attribute__((ext_vector_type(4)));

__device__ __forceinline__ float bf2f(ushort u) {
    return __uint_as_float((uint)u << 16);
}
__device__ __forceinline__ ushort f2bf(float f) {
    uint i = __float_as_uint(f);
    return (ushort)((i + 0x7FFFu + ((i >> 16) & 1u)) >> 16);
}

__device__ __forceinline__ void gload16(const ushort* g, ushort* l) {
    __builtin_amdgcn_global_load_lds(
        (const __attribute__((address_space(1))) void*)g,
        (__attribute__((address_space(3))) void*)l,
        16, 0, 0);
}

// ---- flat fp32 -> bf16 (weights)
__global__ __launch_bounds__(256) void cvt_f32_bf16(const float* __restrict__ s,
                                                    ushort* __restrict__ d, int n)
{
    int i = blockIdx.x * 256 + threadIdx.x;
    if (i < n) d[i] = f2bf(s[i]);
}

// ---- fp32 [R][C] -> bf16 [C][R] transpose+convert, 64x64 tiles, z-sliced
__global__ __launch_bounds__(256) void cvt_transpose_f32(const float* __restrict__ src,
                                                         ushort* __restrict__ dst,
                                                         int R, int C,
                                                         long ssS, long ssD)
{
    __shared__ ushort Ls[64][72];
    int t = threadIdx.x;
    long z = blockIdx.z;
    src += z * ssS; dst += z * ssD;
    int c0 = blockIdx.x * 64, r0 = blockIdx.y * 64;
    {
        int r = t >> 2, cs = t & 3;
        const float* gp = src + (size_t)(r0 + r) * C + c0 + cs * 16;
        ushort tmp[16];
        #pragma unroll
        for (int q = 0; q < 4; ++q) {
            float4 v = *(const float4*)(gp + q * 4);
            tmp[q*4+0] = f2bf(v.x); tmp[q*4+1] = f2bf(v.y);
            tmp[q*4+2] = f2bf(v.z); tmp[q*4+3] = f2bf(v.w);
        }
        *(uint4*)&Ls[r][cs * 16]     = *(uint4*)&tmp[0];
        *(uint4*)&Ls[r][cs * 16 + 8] = *(uint4*)&tmp[8];
    }
    __syncthreads();
    {
        int cc = t & 63, seg = t >> 6;
        ushort tmp[16];
        #pragma unroll
        for (int j = 0; j < 16; ++j) tmp[j] = Ls[seg * 16 + j][cc];
        ushort* op = dst + (size_t)(c0 + cc) * R + r0 + seg * 16;
        *(uint4*)(op)     = *(uint4*)&tmp[0];
        *(uint4*)(op + 8) = *(uint4*)&tmp[8];
    }
}

// ---- bf16 [R][C] -> bf16 [C][R] transpose, 64x64 tiles, z-sliced
__global__ __launch_bounds__(256) void transpose_bf16(const ushort* __restrict__ src,
                                                      ushort* __restrict__ dst,
                                                      int R, int C,
                                                      long ssS, long ssD)
{
    __shared__ ushort Ls[64][72];
    int t = threadIdx.x;
    long z = blockIdx.z;
    src += z * ssS; dst += z * ssD;
    int c0 = blockIdx.x * 64, r0 = blockIdx.y * 64;
    {
        int r = t >> 2, cs = t & 3;
        const ushort* gp = src + (size_t)(r0 + r) * C + c0 + cs * 16;
        *(uint4*)&Ls[r][cs * 16]     = *(const uint4*)(gp);
        *(uint4*)&Ls[r][cs * 16 + 8] = *(const uint4*)(gp + 8);
    }
    __syncthreads();
    {
        int cc = t & 63, seg = t >> 6;
        ushort tmp[16];
        #pragma unroll
        for (int j = 0; j < 16; ++j) tmp[j] = Ls[seg * 16 + j][cc];
        ushort* op = dst + (size_t)(c0 + cc) * R + r0 + seg * 16;
        *(uint4*)(op)     = *(uint4*)&tmp[0];
        *(uint4*)(op + 8) = *(uint4*)&tmp[8];
    }
}

// ---- V [b][384+r][256][256] -> Vt [s=b*192+r][256][256]^T
__global__ __launch_bounds__(256) void transpose_v(const ushort* __restrict__ post,
                                                   ushort* __restrict__ vt)
{
    __shared__ ushort Ls[64][72];
    int t = threadIdx.x;
    int s = blockIdx.z;
    int b = s / 192, r = s - b * 192;
    const ushort* src = post + ((size_t)b * 576 + 384 + r) * HW;
    ushort*       dst = vt + (size_t)s * HW;
    int c0 = blockIdx.x * 64, r0 = blockIdx.y * 64;
    {
        int rr = t >> 2, cs = t & 3;
        const ushort* gp = src + (size_t)(r0 + rr) * IMW + c0 + cs * 16;
        *(uint4*)&Ls[rr][cs * 16]     = *(const uint4*)(gp);
        *(uint4*)&Ls[rr][cs * 16 + 8] = *(const uint4*)(gp + 8);
    }
    __syncthreads();
    {
        int cc = t & 63, seg = t >> 6;
        ushort tmp[16];
        #pragma unroll
        for (int j = 0; j < 16; ++j) tmp[j] = Ls[seg * 16 + j][cc];
        ushort* op = dst + (size_t)(c0 + cc) * IMW + r0 + seg * 16;
        *(uint4*)(op)     = *(uint4*)&tmp[0];
        *(uint4*)(op + 8) = *(uint4*)&tmp[8];
    }
}

// ---- MFMA GEMM: D[m][n] = sum_k A[m][k]*B[n][k] (+bias[m])
// 1D grid, XCD-gather swizzle. Double-buffered LDS; global_load_lds staging
// for tile k+1 issued before computing tile k; ONE barrier per K-iter.
__global__ __launch_bounds__(256) void gemm_mfma(const ushort* __restrict__ A, int lda, long sliceA,
                                                 const ushort* __restrict__ B, int ldb, long sliceB,
                                                 void* __restrict__ Dp, int ldd, long sliceD,
                                                 const float* __restrict__ bias,
                                                 int K, int outF32, int NM, int NN)
{
    // decode: r=lin&7, k=lin>>3, m=k%NM, g=(k/NM)*8+r, n=g%NN, z=g/NN
    int lin = blockIdx.x;
    int r8 = lin & 7, kk_ = lin >> 3;
    int m = kk_ % NM, fg = kk_ / NM;
    int g = fg * 8 + r8;
    int nt_ = g % NN;
    long z = g / NN;
    int m0 = m * 64;
    int n0 = nt_ * 256;

    __shared__ ushort Ws[2][64][32];      // A tiles (dbuf)
    __shared__ ushort Xs[2][256][32];     // B tiles (dbuf)
    int t = threadIdx.x, wv = t >> 6, lane = t & 63;
    int fr = lane & 15, sg = lane >> 4;
    A += z * sliceA; B += z * sliceB;

    int rl   = wv * 16 + (lane >> 2);               // staging row in 64-group
    int chnk = (lane & 3) ^ ((lane >> 3) & 3);      // swizzled k-chunk (write side)
    const ushort* srcA  = A + (size_t)(m0 + rl) * lda + chnk * 8;
    const ushort* srcB0 = B + (size_t)(n0 +       rl) * ldb + chnk * 8;
    const ushort* srcB1 = B + (size_t)(n0 +  64 + rl) * ldb + chnk * 8;
    const ushort* srcB2 = B + (size_t)(n0 + 128 + rl) * ldb + chnk * 8;
    const ushort* srcB3 = B + (size_t)(n0 + 192 + rl) * ldb + chnk * 8;

    int sp = sg ^ ((fr >> 1) & 3);                  // read-side slot swizzle

    f32x4 acc[4][4];
    #pragma unroll
    for (int i = 0; i < 4; ++i)
        #pragma unroll
        for (int j = 0; j < 4; ++j) acc[i][j] = (f32x4){0.f, 0.f, 0.f, 0.f};

    // prologue: stage tile 0 into buf 0
    gload16(srcA,  &Ws[0][wv * 16][0]);
    gload16(srcB0, &Xs[0][      wv * 16][0]);
    gload16(srcB1, &Xs[0][ 64 + wv * 16][0]);
    gload16(srcB2, &Xs[0][128 + wv * 16][0]);
    gload16(srcB3, &Xs[0][192 + wv * 16][0]);
    __syncthreads();

    int nkit = K >> 5;   // 6 for K=192
    for (int kit = 0; kit < nkit; ++kit) {
        int cur = kit & 1;
        if (kit + 1 < nkit) {       // issue next tile into other buffer NOW
            int kn = (kit + 1) * 32;
            gload16(srcA  + kn, &Ws[cur ^ 1][wv * 16][0]);
            gload16(srcB0 + kn, &Xs[cur ^ 1][      wv * 16][0]);
            gload16(srcB1 + kn, &Xs[cur ^ 1][ 64 + wv * 16][0]);
            gload16(srcB2 + kn, &Xs[cur ^ 1][128 + wv * 16][0]);
            gload16(srcB3 + kn, &Xs[cur ^ 1][192 + wv * 16][0]);
        }
        bf16x8 a[4];
        #pragma unroll
        for (int i = 0; i < 4; ++i)
            a[i] = *(const bf16x8*)&Ws[cur][i * 16 + fr][sp * 8];
        #pragma unroll
        for (int j = 0; j < 4; ++j) {
            bf16x8 b = *(const bf16x8*)&Xs[cur][wv * 64 + j * 16 + fr][sp * 8];
            #pragma unroll
            for (int i = 0; i < 4; ++i)
                acc[i][j] = __builtin_amdgcn_mfma_f32_16x16x32_bf16(a[i], b, acc[i][j], 0, 0, 0);
        }
        __syncthreads();   // drains next-tile stage; protects buf[cur] overwrite
    }

    int nw0 = n0 + wv * 64;
    int rbase = sg * 4;
    if (outF32) {
        float* D = (float*)Dp + z * sliceD;
        #pragma unroll
        for (int i = 0; i < 4; ++i) {
            #pragma unroll
            for (int r_ = 0; r_ < 4; ++r_) {
                int mrow = m0 + i * 16 + rbase + r_;
                float bv = bias ? bias[mrow] : 0.f;
                #pragma unroll
                for (int j = 0; j < 4; ++j)
                    D[(size_t)mrow * ldd + nw0 + j * 16 + fr] = acc[i][j][r_] + bv;
            }
        }
    } else {
        ushort* D = (ushort*)Dp + z * sliceD;
        #pragma unroll
        for (int i = 0; i < 4; ++i) {
            #pragma unroll
            for (int r_ = 0; r_ < 4; ++r_) {
                int mrow = m0 + i * 16 + rbase + r_;
                float bv = bias ? bias[mrow] : 0.f;
                #pragma unroll
                for (int j = 0; j < 4; ++j)
                    D[(size_t)mrow * ldd + nw0 + j * 16 + fr] = f2bf(acc[i][j][r_] + bv);
            }
        }
    }
}

// ---- fused attention: per (m-tile 64, slice s): S=QK^T*t, softmax, O=P@Vt
// 1D grid, XCD-gather swizzle. Q/K/Vt staged via global_load_lds + swizzle.
__global__ __launch_bounds__(256) void attn_fused(const ushort* __restrict__ post,
                                                  const ushort* __restrict__ vt,
                                                  const float* __restrict__ temp,
                                                  ushort* __restrict__ O)
{
    __shared__ ushort Ws[64][32];     // Q tile
    __shared__ ushort Xs[256][32];    // K then Vt tile
    __shared__ ushort Ps[64][264];    // P (bf16)
    int t = threadIdx.x, wv = t >> 6, lane = t & 63;
    int fr = lane & 15, sg = lane >> 4;
    int lin = blockIdx.x;
    int r8 = lin & 7, k_ = lin >> 3;
    int mtile = k_ & 3, fg = k_ >> 2;
    int s = fg * 8 + r8;
    int b = s / 192, ch = s - b * 192;
    const ushort* Aq = post + ((size_t)b * 576 + ch) * HW;
    const ushort* Bk = Aq + (size_t)192 * HW;
    const ushort* Vt = vt + (size_t)s * HW;
    int m0 = mtile * 64;

    int rl   = wv * 16 + (lane >> 2);
    int chnk = (lane & 3) ^ ((lane >> 3) & 3);
    int sp   = sg ^ ((fr >> 1) & 3);
    const ushort* srcQ  = Aq + (size_t)(m0 + rl) * IMW + chnk * 8;
    const ushort* srcK0 = Bk + (size_t)(      rl) * IMW + chnk * 8;
    const ushort* srcK1 = Bk + (size_t)( 64 + rl) * IMW + chnk * 8;
    const ushort* srcK2 = Bk + (size_t)(128 + rl) * IMW + chnk * 8;
    const ushort* srcK3 = Bk + (size_t)(192 + rl) * IMW + chnk * 8;
    const ushort* srcV0 = Vt + (size_t)(      rl) * IMW + chnk * 8;
    const ushort* srcV1 = Vt + (size_t)( 64 + rl) * IMW + chnk * 8;
    const ushort* srcV2 = Vt + (size_t)(128 + rl) * IMW + chnk * 8;
    const ushort* srcV3 = Vt + (size_t)(192 + rl) * IMW + chnk * 8;

    f32x4 acc[16];
    #pragma unroll
    for (int i = 0; i < 16; ++i) acc[i] = (f32x4){0.f, 0.f, 0.f, 0.f};

    for (int k0 = 0; k0 < 256; k0 += 32) {
        gload16(srcQ  + k0, &Ws[wv * 16][0]);
        gload16(srcK0 + k0, &Xs[      wv * 16][0]);
        gload16(srcK1 + k0, &Xs[ 64 + wv * 16][0]);
        gload16(srcK2 + k0, &Xs[128 + wv * 16][0]);
        gload16(srcK3 + k0, &Xs[192 + wv * 16][0]);
        __syncthreads();
        bf16x8 a = *(const bf16x8*)&Ws[wv * 16 + fr][sp * 8];
        #pragma unroll
        for (int nt = 0; nt < 16; ++nt) {
            bf16x8 bfrag = *(const bf16x8*)&Xs[nt * 16 + fr][sp * 8];
            acc[nt] = __builtin_amdgcn_mfma_f32_16x16x32_bf16(a, bfrag, acc[nt], 0, 0, 0);
        }
        __syncthreads();
    }

    float tv = temp[ch >> 5];
    #pragma unroll
    for (int r_ = 0; r_ < 4; ++r_) {
        float v[16];
        float mx = -3.4e38f;
        #pragma unroll
        for (int nt = 0; nt < 16; ++nt) { v[nt] = acc[nt][r_] * tv; mx = fmaxf(mx, v[nt]); }
        #pragma unroll
        for (int sh = 1; sh < 16; sh <<= 1) mx = fmaxf(mx, __shfl_xor(mx, sh, 64));
        float sum = 0.f;
        #pragma unroll
        for (int nt = 0; nt < 16; ++nt) { v[nt] = __expf(v[nt] - mx); sum += v[nt]; }
        #pragma unroll
        for (int sh = 1; sh < 16; sh <<= 1) sum += __shfl_xor(sum, sh, 64);
        float inv = 1.f / sum;
        int ml = wv * 16 + sg * 4 + r_;
        #pragma unroll
        for (int nt = 0; nt < 16; ++nt)
            Ps[ml][fr + nt * 16] = f2bf(v[nt] * inv);
    }

    f32x4 acc2[16];
    #pragma unroll
    for (int i = 0; i < 16; ++i) acc2[i] = (f32x4){0.f, 0.f, 0.f, 0.f};

    for (int y0 = 0; y0 < 256; y0 += 32) {
        gload16(srcV0 + y0, &Xs[      wv * 16][0]);
        gload16(srcV1 + y0, &Xs[ 64 + wv * 16][0]);
        gload16(srcV2 + y0, &Xs[128 + wv * 16][0]);
        gload16(srcV3 + y0, &Xs[192 + wv * 16][0]);
        __syncthreads();
        bf16x8 a = *(const bf16x8*)&Ps[wv * 16 + fr][y0 + sg * 8];
        #pragma unroll
        for (int nt = 0; nt < 16; ++nt) {
            bf16x8 bfrag = *(const bf16x8*)&Xs[nt * 16 + fr][sp * 8];
            acc2[nt] = __builtin_amdgcn_mfma_f32_16x16x32_bf16(a, bfrag, acc2[nt], 0, 0, 0);
        }
        __syncthreads();
    }

    ushort* Op = O + (size_t)s * HW;
    int mrow = m0 + wv * 16 + sg * 4;
    #pragma unroll
    for (int r_ = 0; r_ < 4; ++r_) {
        #pragma unroll
        for (int nt = 0; nt < 16; ++nt)
            Op[(size_t)(mrow + r_) * IMW + fr + nt * 16] = f2bf(acc2[nt][r_]);
    }
}

// ---- depthwise 3x3 SAME + fused L2 row-norm, register-staged, shuffle halo
__global__ __launch_bounds__(256) void dw3x3_l2norm(const ushort* __restrict__ in,
                                                    const float* __restrict__ w,
                                                    const float* __restrict__ bias,
                                                    ushort* __restrict__ out)
{
    int t = threadIdx.x;
    int lane = t & 63, wv = t >> 6;
    int ch = blockIdx.y;
    int r0 = blockIdx.x * 16 + wv * 4;
    const ushort* img  = in  + ((size_t)blockIdx.z * 576 + ch) * HW;
    ushort*       outp = out + ((size_t)blockIdx.z * 576 + ch) * HW;
    int px = lane * 4;

    float rv[6][4], lv[6], rx[6];
    #pragma unroll
    for (int i = 0; i < 6; ++i) {
        int rr = r0 - 1 + i;
        if ((unsigned)rr <= 255u) {
            ushort4 cv = *(const ushort4*)&img[(size_t)rr * IMW + px];
            rv[i][0] = bf2f(cv.x); rv[i][1] = bf2f(cv.y);
            rv[i][2] = bf2f(cv.z); rv[i][3] = bf2f(cv.w);
        } else {
            rv[i][0] = rv[i][1] = rv[i][2] = rv[i][3] = 0.f;
        }
        float l = __shfl_up(rv[i][3], 1, 64);
        lv[i] = (lane == 0) ? 0.f : l;
        float r = __shfl_down(rv[i][0], 1, 64);
        rx[i] = (lane == 63) ? 0.f : r;
    }

    const float* wch = w + ch * 9;
    float bv = bias[ch];
    bool do_norm = (ch < 384);

    #pragma unroll
    for (int j = 0; j < 4; ++j) {
        float a0 = bv, a1 = bv, a2 = bv, a3 = bv;
        #pragma unroll
        for (int dy = 0; dy < 3; ++dy) {
            int i = j + dy;
            float w0 = wch[dy * 3], w1 = wch[dy * 3 + 1], w2 = wch[dy * 3 + 2];
            a0 += lv[i]    * w0 + rv[i][0] * w1 + rv[i][1] * w2;
            a1 += rv[i][0] * w0 + rv[i][1] * w1 + rv[i][2] * w2;
            a2 += rv[i][1] * w0 + rv[i][2] * w1 + rv[i][3] * w2;
            a3 += rv[i][2] * w0 + rv[i][3] * w1 + rx[i]    * w2;
        }
        if (do_norm) {
            float ss = a0 * a0 + a1 * a1 + a2 * a2 + a3 * a3;
            #pragma unroll
            for (int m = 1; m < 64; m <<= 1) ss += __shfl_xor(ss, m, 64);
            float inv = 1.0f / fmaxf(sqrtf(ss), 1e-12f);
            a0 *= inv; a1 *= inv; a2 *= inv; a3 *= inv;
        }
        ushort4 o;
        o.x = f2bf(a0); o.y = f2bf(a1); o.z = f2bf(a2); o.w = f2bf(a3);
        *(ushort4*)&outp[(size_t)(r0 + j) * IMW + px] = o;
    }
}

extern "C" void kernel_launch(void* const* d_in, const int* in_sizes, int n_in,
                              void* d_out, int out_size, void* d_ws, size_t ws_size,
                              hipStream_t stream)
{
    const float* x      = (const float*)d_in[0];
    const float* qkv_w  = (const float*)d_in[1];
    const float* qkv_b  = (const float*)d_in[2];
    const float* dw_w   = (const float*)d_in[3];
    const float* dw_b   = (const float*)d_in[4];
    const float* proj_w = (const float*)d_in[5];
    const float* proj_b = (const float*)d_in[6];
    const float* temp   = (const float*)d_in[7];
    float* out = (float*)d_out;

    const size_t off_wq   = 0;
    const size_t off_wp   = 110592;
    const size_t off_pre  = 262144;
    const size_t off_post = off_pre + (size_t)4 * 576 * HW;
    const size_t off_xt   = off_post + (size_t)4 * 576 * HW;
    const size_t total_us = off_xt + (size_t)4 * 192 * HW;
    if (ws_size < total_us * sizeof(ushort)) return;

    ushort* wsb  = (ushort*)d_ws;
    ushort* wq   = wsb + off_wq;
    ushort* wp   = wsb + off_wp;
    ushort* pre  = wsb + off_pre;
    ushort* post = wsb + off_post;
    ushort* xt   = wsb + off_xt;
    ushort* Obuf = pre;
    ushort* Otb  = pre + (size_t)4 * 192 * HW;

    const long SL = (long)192 * HW;

    cvt_f32_bf16<<<dim3(432), 256, 0, stream>>>(qkv_w, wq, 110592);
    cvt_f32_bf16<<<dim3(144), 256, 0, stream>>>(proj_w, wp, 36864);

    cvt_transpose_f32<<<dim3(1024, 3, 4), 256, 0, stream>>>(x, xt, 192, HW, SL, SL);
    // qkv: NM=9, NN=256, 4 batches -> 9216 blocks
    gemm_mfma<<<dim3(9 * 256 * 4), 256, 0, stream>>>(wq, 192, 0, xt, 192, SL,
                                                     pre, HW, (long)576 * HW,
                                                     qkv_b, 192, 0, 9, 256);
    dw3x3_l2norm<<<dim3(16, 576, 4), 256, 0, stream>>>(pre, dw_w, dw_b, post);
    transpose_v<<<dim3(4, 4, 768), 256, 0, stream>>>(post, xt);
    attn_fused<<<dim3(4 * 768), 256, 0, stream>>>(post, xt, temp, Obuf);
    transpose_bf16<<<dim3(1024, 3, 4), 256, 0, stream>>>(Obuf, Otb, 192, HW, SL, SL);
    // proj: NM=3, NN=256, 4 batches -> 3072 blocks
    gemm_mfma<<<dim3(3 * 256 * 4), 256, 0, stream>>>(wp, 192, 0, Otb, 192, SL,
                                                     out, HW, SL,
                                                     proj_b, 192, 1, 3, 256);
}